// Round 6
// baseline (2135.046 us; speedup 1.0000x reference)
//
#include <hip/hip_runtime.h>

#define BN_SCALE 0.9999950000374997f  // 1/sqrt(1+1e-5)

// ---------------- sqnorm: sq[b,n] = sum_c X[b,c,n]^2 ----------------
__global__ void sqnorm_kernel(const float* __restrict__ X, int xStrideB,
                              int C, int Np, float* __restrict__ sq) {
  int b = blockIdx.y;
  int n = blockIdx.x * blockDim.x + threadIdx.x;
  if (n >= Np) return;
  const float* p = X + (long)b * xStrideB + n;
  float s = 0.f;
  for (int c = 0; c < C; ++c) { float v = p[(long)c * Np]; s = fmaf(v, v, s); }
  sq[(long)b * Np + n] = s;
}

// ---------------- knn4: 4 queries per block; dot phase shared, per-wave top-k extract ----------------
__global__ void knn4_kernel(const float* __restrict__ Q, int qStrideB,
                            const float* __restrict__ Xc, int cStrideB,
                            const float* __restrict__ sqQ, const float* __restrict__ sqC,
                            int C, int M, int N, int k, int* __restrict__ idxOut) {
  __shared__ float qv[4][256];
  __shared__ float negd[4][2048];
  int b = blockIdx.y, q0 = blockIdx.x * 4, tid = threadIdx.x;
  for (int e = tid; e < 4 * C; e += 256) {
    int qq = e / C, c = e % C;
    qv[qq][c] = Q[(long)b * qStrideB + (long)c * M + (q0 + qq)];
  }
  __syncthreads();
  float s0 = sqQ[(long)b * M + q0 + 0];
  float s1 = sqQ[(long)b * M + q0 + 1];
  float s2 = sqQ[(long)b * M + q0 + 2];
  float s3 = sqQ[(long)b * M + q0 + 3];
  const float* cb = Xc + (long)b * cStrideB;
  const float* sc = sqC + (long)b * N;
  for (int m = tid; m < N; m += 256) {
    float d0 = 0.f, d1 = 0.f, d2 = 0.f, d3 = 0.f;
    for (int c = 0; c < C; ++c) {
      float xv = cb[(long)c * N + m];
      d0 = fmaf(qv[0][c], xv, d0);
      d1 = fmaf(qv[1][c], xv, d1);
      d2 = fmaf(qv[2][c], xv, d2);
      d3 = fmaf(qv[3][c], xv, d3);
    }
    float scm = sc[m];
    negd[0][m] = 2.f * d0 - s0 - scm;
    negd[1][m] = 2.f * d1 - s1 - scm;
    negd[2][m] = 2.f * d2 - s2 - scm;
    negd[3][m] = 2.f * d3 - s3 - scm;
  }
  __syncthreads();
  int lane = tid & 63, w = tid >> 6;
  float* row = negd[w];
  int* outp = idxOut + ((long)b * M + (q0 + w)) * k;
  for (int kk = 0; kk < k; ++kk) {
    float best = -INFINITY; int bi = N;
    for (int m = lane; m < N; m += 64) {
      float v = row[m];
      if (v > best) { best = v; bi = m; }
    }
    for (int off = 32; off > 0; off >>= 1) {
      float ov = __shfl_xor(best, off);
      int   oi = __shfl_xor(bi, off);
      if (ov > best || (ov == best && oi < bi)) { best = ov; bi = oi; }
    }
    if (lane == (bi & 63)) row[bi] = -INFINITY;
    if (lane == 0) outp[kk] = bi;
  }
}

// ---------------- gemmT: outT[b][n][o] = sum_c W[o*ldw+c] * X[b][c][n] ----------------
__global__ void gemmT_kernel(const float* __restrict__ X, int xStrideB, int C, int Np,
                             const float* __restrict__ W, int ldw, int O,
                             float* __restrict__ outT) {
  __shared__ float Wt[16][65];
  __shared__ float Xt[16][65];
  int b = blockIdx.z;
  int n0 = blockIdx.x * 64, o0 = blockIdx.y * 64;
  int tid = threadIdx.x;
  int to = tid % 16, tn = tid / 16;
  float acc[4][4] = {};
  for (int c0 = 0; c0 < C; c0 += 16) {
    for (int e = tid; e < 16 * 64; e += 256) {
      int oo = e / 16, kk = e % 16;
      int c = c0 + kk, o = o0 + oo;
      Wt[kk][oo] = (c < C && o < O) ? W[(long)o * ldw + c] : 0.f;
    }
    for (int e = tid; e < 16 * 64; e += 256) {
      int kk = e / 64, nn = e % 64;
      int c = c0 + kk, n = n0 + nn;
      Xt[kk][nn] = (c < C && n < Np) ? X[(long)b * xStrideB + (long)c * Np + n] : 0.f;
    }
    __syncthreads();
    for (int kk = 0; kk < 16; ++kk) {
      float xv[4], wv[4];
      for (int i = 0; i < 4; ++i) xv[i] = Xt[kk][tn + 16 * i];
      for (int j = 0; j < 4; ++j) wv[j] = Wt[kk][to + 16 * j];
      for (int i = 0; i < 4; ++i)
        for (int j = 0; j < 4; ++j) acc[i][j] = fmaf(xv[i], wv[j], acc[i][j]);
    }
    __syncthreads();
  }
  for (int i = 0; i < 4; ++i) {
    int n = n0 + tn + 16 * i;
    if (n >= Np) continue;
    for (int j = 0; j < 4; ++j) {
      int o = o0 + to + 16 * j;
      if (o < O) outT[((long)b * Np + n) * O + o] = acc[i][j];
    }
  }
}

// ---------------- ecfinish: out[b,o,n] = lrelu(bn(S[n,o]-P[n,o] + max/min_k P[idx[n,k],o])) ----------------
__global__ void ecfinish_kernel(const float* __restrict__ Pt, const float* __restrict__ St,
                                const int* __restrict__ idx, int k, int O, int Np,
                                const float* __restrict__ g, const float* __restrict__ bb,
                                float* __restrict__ outp, long oStrideB) {
  int b = blockIdx.y;
  int n = blockIdx.x * blockDim.y + threadIdx.y;
  int o = threadIdx.x;
  const float* PtB = Pt + (long)b * Np * O;
  const float* StB = St + (long)b * Np * O;
  const int* ip = idx + ((long)b * Np + n) * k;
  float mx = -INFINITY, mn = INFINITY;
  for (int kk = 0; kk < k; ++kk) {
    float v = PtB[(long)ip[kk] * O + o];
    mx = fmaxf(mx, v); mn = fminf(mn, v);
  }
  float ctrP = PtB[(long)n * O + o];
  float ctrS = StB[(long)n * O + o];
  float gs = g[o] * BN_SCALE;
  float m = (gs >= 0.f) ? mx : mn;
  float h = (ctrS - ctrP + m) * gs + bb[o];
  outp[(long)b * oStrideB + (long)o * Np + n] = h >= 0.f ? h : 0.2f * h;
}

// ---------------- gemm_colmax: tile GEMM + lrelu(bn()) + max over n-tile -> partial[b][nt][o] ----------------
__global__ void gemm_colmax_kernel(const float* __restrict__ X, int xStrideB, int C, int Np,
                                   const float* __restrict__ W, int ldw, int O,
                                   const float* __restrict__ g, const float* __restrict__ bb,
                                   float* __restrict__ partial) {
  __shared__ float Wt[16][65];
  __shared__ float Xt[16][65];
  int b = blockIdx.z;
  int n0 = blockIdx.x * 64, o0 = blockIdx.y * 64;
  int tid = threadIdx.x;
  int to = tid % 16, tn = tid / 16;
  float acc[4][4] = {};
  for (int c0 = 0; c0 < C; c0 += 16) {
    for (int e = tid; e < 16 * 64; e += 256) {
      int oo = e / 16, kk = e % 16;
      int c = c0 + kk, o = o0 + oo;
      Wt[kk][oo] = (c < C && o < O) ? W[(long)o * ldw + c] : 0.f;
    }
    for (int e = tid; e < 16 * 64; e += 256) {
      int kk = e / 64, nn = e % 64;
      int c = c0 + kk, n = n0 + nn;
      Xt[kk][nn] = (c < C && n < Np) ? X[(long)b * xStrideB + (long)c * Np + n] : 0.f;
    }
    __syncthreads();
    for (int kk = 0; kk < 16; ++kk) {
      float xv[4], wv[4];
      for (int i = 0; i < 4; ++i) xv[i] = Xt[kk][tn + 16 * i];
      for (int j = 0; j < 4; ++j) wv[j] = Wt[kk][to + 16 * j];
      for (int i = 0; i < 4; ++i)
        for (int j = 0; j < 4; ++j) acc[i][j] = fmaf(xv[i], wv[j], acc[i][j]);
    }
    __syncthreads();
  }
  float vm[4];
  for (int j = 0; j < 4; ++j) {
    int o = o0 + to + 16 * j;
    float gs = g[o] * BN_SCALE, bo = bb[o];
    float m = -INFINITY;
    for (int i = 0; i < 4; ++i) {
      float h = acc[i][j] * gs + bo;
      h = h >= 0.f ? h : 0.2f * h;
      m = fmaxf(m, h);
    }
    vm[j] = m;
  }
  for (int j = 0; j < 4; ++j) Xt[tn][to + 16 * j] = vm[j];
  __syncthreads();
  for (int s = 8; s > 0; s >>= 1) {
    if (tn < s)
      for (int j = 0; j < 4; ++j)
        Xt[tn][to + 16 * j] = fmaxf(Xt[tn][to + 16 * j], Xt[tn + s][to + 16 * j]);
    __syncthreads();
  }
  if (tn == 0)
    for (int j = 0; j < 4; ++j) {
      int o = o0 + to + 16 * j;
      partial[((long)b * gridDim.x + blockIdx.x) * O + o] = Xt[0][to + 16 * j];
    }
}

// ---------------- colmax_finish: out[b][o] = max_t partial[b][t][o] ----------------
__global__ void colmax_finish_kernel(const float* __restrict__ partial, int NT, int O,
                                     float* __restrict__ outp) {
  int b = blockIdx.y;
  int o = blockIdx.x * 256 + threadIdx.x;
  if (o >= O) return;
  float m = -INFINITY;
  for (int t = 0; t < NT; ++t) m = fmaxf(m, partial[((long)b * NT + t) * O + o]);
  outp[(long)b * O + o] = m;
}

// ---------------- FPS: SINGLE WAVE per batch; coords+dist in VGPRs.
// Register arrays are initialized FROM LDS (non-rematerializable loads) so the
// compiler cannot re-load them from global each iteration (R4's 92-VGPR remat bug).
__global__ void __launch_bounds__(64, 1) fps_kernel(const float* __restrict__ xyz, int N, int M,
                                                    int* __restrict__ fpsIdx, float* __restrict__ node1) {
  #pragma clang fp contract(off)
  __shared__ float sx[2048], sy[2048], sz[2048];
  __shared__ int fidx[512];
  int b = blockIdx.x, lane = threadIdx.x;
  const float* xb = xyz + (long)b * 3 * N;
  for (int n = lane; n < N; n += 64) {
    sx[n] = xb[n]; sy[n] = xb[N + n]; sz[n] = xb[2 * N + n];
  }
  __syncthreads();  // single wave: drains LDS writes
  int base = lane * 32;
  float px[32], py[32], pz[32], dist[32];
  #pragma unroll
  for (int i = 0; i < 32; ++i) {
    px[i] = sx[base + i];   // LDS-sourced: cannot be rematerialized -> stays in VGPRs
    py[i] = sy[base + i];
    pz[i] = sz[base + i];
    dist[i] = 1e10f;
  }
  int last = 0;
  for (int it = 0; it < M; ++it) {
    if (lane == 0) fidx[it] = last;
    float lx = sx[last], ly = sy[last], lz = sz[last];  // same-address broadcast
    float best = -INFINITY; int bi = N;
    #pragma unroll
    for (int i = 0; i < 32; ++i) {
      float dx = px[i] - lx, dy = py[i] - ly, dz = pz[i] - lz;
      float dx2 = dx * dx, dy2 = dy * dy, dz2 = dz * dz;
      float d = (dx2 + dy2) + dz2;
      float dn = dist[i];
      if (d < dn) dn = d;
      dist[i] = dn;
      if (dn > best) { best = dn; bi = base + i; }  // ascending -> first max in lane kept
    }
    // value-only butterfly -> global max in all lanes
    float gmax = best;
    #pragma unroll
    for (int off = 32; off > 0; off >>= 1) {
      float ov = __shfl_xor(gmax, off);
      gmax = fmaxf(gmax, ov);
    }
    // first (smallest) lane holding gmax gives the first-occurrence argmax
    unsigned long long m = __ballot(best == gmax);
    int srcLane = (int)(__ffsll((long long)m) - 1);
    last = __shfl(bi, srcLane);
  }
  // flush fpsIdx + node1 from LDS
  for (int e = lane; e < M; e += 64) fpsIdx[(long)b * M + e] = fidx[e];
  for (int e = lane; e < 3 * M; e += 64) {
    int c = e / M, i = e % M;
    int src = fidx[i];
    float v = (c == 0) ? sx[src] : (c == 1) ? sy[src] : sz[src];
    node1[(long)b * 3 * M + e] = v;
  }
}

// ---------------- gather: out[b,c,i] = X[b,c,idx[b,i]] ----------------
__global__ void gather_kernel(const float* __restrict__ X, int xStrideB, int C, int N,
                              const int* __restrict__ idx, int M,
                              float* __restrict__ outp, int oStrideB, int B) {
  long t = (long)blockIdx.x * blockDim.x + threadIdx.x;
  long total = (long)B * C * M;
  if (t >= total) return;
  int i = (int)(t % M);
  int c = (int)((t / M) % C);
  int b = (int)(t / ((long)C * M));
  int src = idx[(long)b * M + i];
  outp[(long)b * oStrideB + (long)c * M + i] = X[(long)b * xStrideB + (long)c * N + src];
}

// ---------------- gathermax: out[b,c,i] = max_k X[b,c,idx[b,i,k]] ----------------
__global__ void gathermax_kernel(const float* __restrict__ X, int xStrideB, int C, int N,
                                 const int* __restrict__ idx, int k, int M,
                                 float* __restrict__ outp, int oStrideB, int B) {
  long t = (long)blockIdx.x * blockDim.x + threadIdx.x;
  long total = (long)B * C * M;
  if (t >= total) return;
  int i = (int)(t % M);
  int c = (int)((t / M) % C);
  int b = (int)(t / ((long)C * M));
  const int* ip = idx + ((long)b * M + i) * k;
  const float* xb = X + (long)b * xStrideB + (long)c * N;
  float best = -INFINITY;
  for (int kk = 0; kk < k; ++kk) best = fmaxf(best, xb[ip[kk]]);
  outp[(long)b * oStrideB + (long)c * M + i] = best;
}

// ---------------- head: v=[vf;vs] -> 3-layer MLP -> logits ----------------
__global__ void head_kernel(const float* __restrict__ vf, const float* __restrict__ vs,
                            const float* __restrict__ Wl1, const float* __restrict__ g6, const float* __restrict__ b6,
                            const float* __restrict__ Wl2, const float* __restrict__ bl2,
                            const float* __restrict__ g7, const float* __restrict__ b7,
                            const float* __restrict__ Wl3, const float* __restrict__ bl3,
                            float* __restrict__ logits) {
  __shared__ float v[2048];
  __shared__ float h1[512];
  __shared__ float h2[256];
  int b = blockIdx.x, tid = threadIdx.x;
  for (int c = tid; c < 1024; c += 256) {
    v[c]        = vf[(long)b * 1024 + c];
    v[1024 + c] = vs[(long)b * 1024 + c];
  }
  __syncthreads();
  for (int o = tid; o < 512; o += 256) {
    const float* wr = Wl1 + (long)o * 2048;
    float s = 0.f;
    for (int c = 0; c < 2048; c += 4) {
      float4 w4 = *(const float4*)(wr + c);
      s = fmaf(w4.x, v[c], s); s = fmaf(w4.y, v[c + 1], s);
      s = fmaf(w4.z, v[c + 2], s); s = fmaf(w4.w, v[c + 3], s);
    }
    float h = s * (g6[o] * BN_SCALE) + b6[o];
    h1[o] = h >= 0.f ? h : 0.2f * h;
  }
  __syncthreads();
  for (int o = tid; o < 256; o += 256) {
    const float* wr = Wl2 + (long)o * 512;
    float s = 0.f;
    for (int c = 0; c < 512; c += 4) {
      float4 w4 = *(const float4*)(wr + c);
      s = fmaf(w4.x, h1[c], s); s = fmaf(w4.y, h1[c + 1], s);
      s = fmaf(w4.z, h1[c + 2], s); s = fmaf(w4.w, h1[c + 3], s);
    }
    s += bl2[o];
    float h = s * (g7[o] * BN_SCALE) + b7[o];
    h2[o] = h >= 0.f ? h : 0.2f * h;
  }
  __syncthreads();
  if (tid < 40) {
    const float* wr = Wl3 + (long)tid * 256;
    float s = 0.f;
    for (int c = 0; c < 256; ++c) s = fmaf(wr[c], h2[c], s);
    logits[(long)b * 40 + tid] = s + bl3[tid];
  }
}

extern "C" void kernel_launch(void* const* d_in, const int* in_sizes, int n_in,
                              void* d_out, int out_size, void* d_ws, size_t ws_size,
                              hipStream_t stream) {
  const float* x   = (const float*)d_in[0];
  const float* W1  = (const float*)d_in[1];
  const float* g1  = (const float*)d_in[2];
  const float* b1  = (const float*)d_in[3];
  const float* W2  = (const float*)d_in[4];
  const float* g2  = (const float*)d_in[5];
  const float* b2  = (const float*)d_in[6];
  const float* W2m = (const float*)d_in[7];
  const float* g2m = (const float*)d_in[8];
  const float* b2m = (const float*)d_in[9];
  const float* W3  = (const float*)d_in[10];
  const float* g3  = (const float*)d_in[11];
  const float* b3  = (const float*)d_in[12];
  const float* W4  = (const float*)d_in[13];
  const float* g4  = (const float*)d_in[14];
  const float* b4  = (const float*)d_in[15];
  const float* W5  = (const float*)d_in[16];
  const float* g5  = (const float*)d_in[17];
  const float* b5  = (const float*)d_in[18];
  const float* Wl1 = (const float*)d_in[19];
  const float* g6  = (const float*)d_in[20];
  const float* b6  = (const float*)d_in[21];
  const float* Wl2 = (const float*)d_in[22];
  const float* bl2 = (const float*)d_in[23];
  const float* g7  = (const float*)d_in[24];
  const float* b7  = (const float*)d_in[25];
  const float* Wl3 = (const float*)d_in[26];
  const float* bl3 = (const float*)d_in[27];
  float* outF = (float*)d_out;

  const int B = 8, N = 2048, K = 20, M = 512, K2 = 10;

  float* ws   = (float*)d_ws;
  float* xt1  = ws;                              // (B,128,N)
  float* xm   = xt1 + (size_t)B * 128 * N;       // (B,256,M)
  float* xc   = xm  + (size_t)B * 256 * M;       // (B,512,M)
  float* Pt   = xc  + (size_t)B * 512 * M;       // (B,N,64)/(B,M,256)
  float* St   = Pt  + (size_t)B * N * 64;
  float* part = St  + (size_t)B * N * 64;        // (B,32,1024)
  float* vf   = part + (size_t)B * 32 * 1024;
  float* vs   = vf  + (size_t)B * 1024;
  float* sqa  = vs  + (size_t)B * 1024;
  float* sqb  = sqa + (size_t)B * N;
  float* sqn  = sqb + (size_t)B * N;
  int*   idxK = (int*)(sqn + (size_t)B * M);
  int*   fpsI = idxK + (size_t)B * N * K;

  float* logits = outF;        // (B,40)
  float* node1  = outF + 320;  // (B,3,M)

  dim3 t256(256);

  // ---- stage 1
  sqnorm_kernel<<<dim3((N + 255) / 256, B), t256, 0, stream>>>(x, 3 * N, 3, N, sqa);
  knn4_kernel<<<dim3(N / 4, B), t256, 0, stream>>>(x, 3 * N, x, 3 * N, sqa, sqa, 3, N, N, K, idxK);
  gemmT_kernel<<<dim3(N / 64, 1, B), t256, 0, stream>>>(x, 3 * N, 3, N, W1,     6, 64, Pt);
  gemmT_kernel<<<dim3(N / 64, 1, B), t256, 0, stream>>>(x, 3 * N, 3, N, W1 + 3, 6, 64, St);
  ecfinish_kernel<<<dim3(N / 4, B), dim3(64, 4), 0, stream>>>(Pt, St, idxK, K, 64, N, g1, b1, xt1, (long)128 * N);

  // FPS
  fps_kernel<<<dim3(B), dim3(64), 0, stream>>>(x, N, M, fpsI, node1);

  // ---- stage 2
  sqnorm_kernel<<<dim3((N + 255) / 256, B), t256, 0, stream>>>(xt1, 128 * N, 64, N, sqb);
  knn4_kernel<<<dim3(N / 4, B), t256, 0, stream>>>(xt1, 128 * N, xt1, 128 * N, sqb, sqb, 64, N, N, K, idxK);
  gemmT_kernel<<<dim3(N / 64, 1, B), t256, 0, stream>>>(xt1, 128 * N, 64, N, W2,      128, 64, Pt);
  gemmT_kernel<<<dim3(N / 64, 1, B), t256, 0, stream>>>(xt1, 128 * N, 64, N, W2 + 64, 128, 64, St);
  ecfinish_kernel<<<dim3(N / 4, B), dim3(64, 4), 0, stream>>>(Pt, St, idxK, K, 64, N, g2, b2,
                                                              xt1 + (size_t)64 * N, (long)128 * N);

  // ---- vf
  gemm_colmax_kernel<<<dim3(N / 64, 1024 / 64, B), t256, 0, stream>>>(xt1, 128 * N, 128, N, W2m, 128, 1024,
                                                                      g2m, b2m, part);
  colmax_finish_kernel<<<dim3(1024 / 256, B), t256, 0, stream>>>(part, N / 64, 1024, vf);

  // ---- nf1 gather
  gather_kernel<<<dim3((B * 128 * M + 255) / 256), t256, 0, stream>>>(xt1, 128 * N, 128, N, fpsI, M, xm, 256 * M, B);

  // ---- aggregate
  sqnorm_kernel<<<dim3((M + 255) / 256, B), t256, 0, stream>>>(node1, 3 * M, 3, M, sqn);
  knn4_kernel<<<dim3(M / 4, B), t256, 0, stream>>>(node1, 3 * M, x, 3 * N, sqn, sqa, 3, M, N, K, idxK);
  gathermax_kernel<<<dim3((B * 128 * M + 255) / 256), t256, 0, stream>>>(xt1, 128 * N, 128, N, idxK, K, M,
                                                                         xm + (size_t)128 * M, 256 * M, B);

  // ---- stage 3
  sqnorm_kernel<<<dim3((M + 255) / 256, B), t256, 0, stream>>>(xm, 256 * M, 256, M, sqb);
  knn4_kernel<<<dim3(M / 4, B), t256, 0, stream>>>(xm, 256 * M, xm, 256 * M, sqb, sqb, 256, M, M, K2, idxK);
  gemmT_kernel<<<dim3(M / 64, 256 / 64, B), t256, 0, stream>>>(xm, 256 * M, 256, M, W3,       512, 256, Pt);
  gemmT_kernel<<<dim3(M / 64, 256 / 64, B), t256, 0, stream>>>(xm, 256 * M, 256, M, W3 + 256, 512, 256, St);
  ecfinish_kernel<<<dim3(M, B), dim3(256, 1), 0, stream>>>(Pt, St, idxK, K2, 256, M, g3, b3, xc, (long)512 * M);

  // ---- stage 4
  sqnorm_kernel<<<dim3((M + 255) / 256, B), t256, 0, stream>>>(xc, 512 * M, 256, M, sqb);
  knn4_kernel<<<dim3(M / 4, B), t256, 0, stream>>>(xc, 512 * M, xc, 512 * M, sqb, sqb, 256, M, M, K2, idxK);
  gemmT_kernel<<<dim3(M / 64, 256 / 64, B), t256, 0, stream>>>(xc, 512 * M, 256, M, W4,       512, 256, Pt);
  gemmT_kernel<<<dim3(M / 64, 256 / 64, B), t256, 0, stream>>>(xc, 512 * M, 256, M, W4 + 256, 512, 256, St);
  ecfinish_kernel<<<dim3(M, B), dim3(256, 1), 0, stream>>>(Pt, St, idxK, K2, 256, M, g4, b4,
                                                           xc + (size_t)256 * M, (long)512 * M);

  // ---- vs
  gemm_colmax_kernel<<<dim3(M / 64, 1024 / 64, B), t256, 0, stream>>>(xc, 512 * M, 512, M, W5, 512, 1024,
                                                                      g5, b5, part);
  colmax_finish_kernel<<<dim3(1024 / 256, B), t256, 0, stream>>>(part, M / 64, 1024, vs);

  // ---- head
  head_kernel<<<dim3(B), t256, 0, stream>>>(vf, vs, Wl1, g6, b6, Wl2, bl2, g7, b7, Wl3, bl3, logits);
}

// Round 7
// 2082.276 us; speedup vs baseline: 1.0253x; 1.0253x over previous
//
#include <hip/hip_runtime.h>

#define BN_SCALE 0.9999950000374997f  // 1/sqrt(1+1e-5)

// ---------------- sqnorm: sq[b,n] = sum_c X[b,c,n]^2 ----------------
__global__ void sqnorm_kernel(const float* __restrict__ X, int xStrideB,
                              int C, int Np, float* __restrict__ sq) {
  int b = blockIdx.y;
  int n = blockIdx.x * blockDim.x + threadIdx.x;
  if (n >= Np) return;
  const float* p = X + (long)b * xStrideB + n;
  float s = 0.f;
  for (int c = 0; c < C; ++c) { float v = p[(long)c * Np]; s = fmaf(v, v, s); }
  sq[(long)b * Np + n] = s;
}

// ---------------- knn4: 4 queries per block; dot phase shared, per-wave top-k extract ----------------
__global__ void knn4_kernel(const float* __restrict__ Q, int qStrideB,
                            const float* __restrict__ Xc, int cStrideB,
                            const float* __restrict__ sqQ, const float* __restrict__ sqC,
                            int C, int M, int N, int k, int* __restrict__ idxOut) {
  __shared__ float qv[4][256];
  __shared__ float negd[4][2048];
  int b = blockIdx.y, q0 = blockIdx.x * 4, tid = threadIdx.x;
  for (int e = tid; e < 4 * C; e += 256) {
    int qq = e / C, c = e % C;
    qv[qq][c] = Q[(long)b * qStrideB + (long)c * M + (q0 + qq)];
  }
  __syncthreads();
  float s0 = sqQ[(long)b * M + q0 + 0];
  float s1 = sqQ[(long)b * M + q0 + 1];
  float s2 = sqQ[(long)b * M + q0 + 2];
  float s3 = sqQ[(long)b * M + q0 + 3];
  const float* cb = Xc + (long)b * cStrideB;
  const float* sc = sqC + (long)b * N;
  for (int m = tid; m < N; m += 256) {
    float d0 = 0.f, d1 = 0.f, d2 = 0.f, d3 = 0.f;
    for (int c = 0; c < C; ++c) {
      float xv = cb[(long)c * N + m];
      d0 = fmaf(qv[0][c], xv, d0);
      d1 = fmaf(qv[1][c], xv, d1);
      d2 = fmaf(qv[2][c], xv, d2);
      d3 = fmaf(qv[3][c], xv, d3);
    }
    float scm = sc[m];
    negd[0][m] = 2.f * d0 - s0 - scm;
    negd[1][m] = 2.f * d1 - s1 - scm;
    negd[2][m] = 2.f * d2 - s2 - scm;
    negd[3][m] = 2.f * d3 - s3 - scm;
  }
  __syncthreads();
  int lane = tid & 63, w = tid >> 6;
  float* row = negd[w];
  int* outp = idxOut + ((long)b * M + (q0 + w)) * k;
  for (int kk = 0; kk < k; ++kk) {
    float best = -INFINITY; int bi = N;
    for (int m = lane; m < N; m += 64) {
      float v = row[m];
      if (v > best) { best = v; bi = m; }
    }
    for (int off = 32; off > 0; off >>= 1) {
      float ov = __shfl_xor(best, off);
      int   oi = __shfl_xor(bi, off);
      if (ov > best || (ov == best && oi < bi)) { best = ov; bi = oi; }
    }
    if (lane == (bi & 63)) row[bi] = -INFINITY;
    if (lane == 0) outp[kk] = bi;
  }
}

// ---------------- gemmT: outT[b][n][o] = sum_c W[o*ldw+c] * X[b][c][n] ----------------
__global__ void gemmT_kernel(const float* __restrict__ X, int xStrideB, int C, int Np,
                             const float* __restrict__ W, int ldw, int O,
                             float* __restrict__ outT) {
  __shared__ float Wt[16][65];
  __shared__ float Xt[16][65];
  int b = blockIdx.z;
  int n0 = blockIdx.x * 64, o0 = blockIdx.y * 64;
  int tid = threadIdx.x;
  int to = tid % 16, tn = tid / 16;
  float acc[4][4] = {};
  for (int c0 = 0; c0 < C; c0 += 16) {
    for (int e = tid; e < 16 * 64; e += 256) {
      int oo = e / 16, kk = e % 16;
      int c = c0 + kk, o = o0 + oo;
      Wt[kk][oo] = (c < C && o < O) ? W[(long)o * ldw + c] : 0.f;
    }
    for (int e = tid; e < 16 * 64; e += 256) {
      int kk = e / 64, nn = e % 64;
      int c = c0 + kk, n = n0 + nn;
      Xt[kk][nn] = (c < C && n < Np) ? X[(long)b * xStrideB + (long)c * Np + n] : 0.f;
    }
    __syncthreads();
    for (int kk = 0; kk < 16; ++kk) {
      float xv[4], wv[4];
      for (int i = 0; i < 4; ++i) xv[i] = Xt[kk][tn + 16 * i];
      for (int j = 0; j < 4; ++j) wv[j] = Wt[kk][to + 16 * j];
      for (int i = 0; i < 4; ++i)
        for (int j = 0; j < 4; ++j) acc[i][j] = fmaf(xv[i], wv[j], acc[i][j]);
    }
    __syncthreads();
  }
  for (int i = 0; i < 4; ++i) {
    int n = n0 + tn + 16 * i;
    if (n >= Np) continue;
    for (int j = 0; j < 4; ++j) {
      int o = o0 + to + 16 * j;
      if (o < O) outT[((long)b * Np + n) * O + o] = acc[i][j];
    }
  }
}

// ---------------- ecfinish: out[b,o,n] = lrelu(bn(S[n,o]-P[n,o] + max/min_k P[idx[n,k],o])) ----------------
__global__ void ecfinish_kernel(const float* __restrict__ Pt, const float* __restrict__ St,
                                const int* __restrict__ idx, int k, int O, int Np,
                                const float* __restrict__ g, const float* __restrict__ bb,
                                float* __restrict__ outp, long oStrideB) {
  int b = blockIdx.y;
  int n = blockIdx.x * blockDim.y + threadIdx.y;
  int o = threadIdx.x;
  const float* PtB = Pt + (long)b * Np * O;
  const float* StB = St + (long)b * Np * O;
  const int* ip = idx + ((long)b * Np + n) * k;
  float mx = -INFINITY, mn = INFINITY;
  for (int kk = 0; kk < k; ++kk) {
    float v = PtB[(long)ip[kk] * O + o];
    mx = fmaxf(mx, v); mn = fminf(mn, v);
  }
  float ctrP = PtB[(long)n * O + o];
  float ctrS = StB[(long)n * O + o];
  float gs = g[o] * BN_SCALE;
  float m = (gs >= 0.f) ? mx : mn;
  float h = (ctrS - ctrP + m) * gs + bb[o];
  outp[(long)b * oStrideB + (long)o * Np + n] = h >= 0.f ? h : 0.2f * h;
}

// ---------------- gemm_colmax: tile GEMM + lrelu(bn()) + max over n-tile -> partial[b][nt][o] ----------------
__global__ void gemm_colmax_kernel(const float* __restrict__ X, int xStrideB, int C, int Np,
                                   const float* __restrict__ W, int ldw, int O,
                                   const float* __restrict__ g, const float* __restrict__ bb,
                                   float* __restrict__ partial) {
  __shared__ float Wt[16][65];
  __shared__ float Xt[16][65];
  int b = blockIdx.z;
  int n0 = blockIdx.x * 64, o0 = blockIdx.y * 64;
  int tid = threadIdx.x;
  int to = tid % 16, tn = tid / 16;
  float acc[4][4] = {};
  for (int c0 = 0; c0 < C; c0 += 16) {
    for (int e = tid; e < 16 * 64; e += 256) {
      int oo = e / 16, kk = e % 16;
      int c = c0 + kk, o = o0 + oo;
      Wt[kk][oo] = (c < C && o < O) ? W[(long)o * ldw + c] : 0.f;
    }
    for (int e = tid; e < 16 * 64; e += 256) {
      int kk = e / 64, nn = e % 64;
      int c = c0 + kk, n = n0 + nn;
      Xt[kk][nn] = (c < C && n < Np) ? X[(long)b * xStrideB + (long)c * Np + n] : 0.f;
    }
    __syncthreads();
    for (int kk = 0; kk < 16; ++kk) {
      float xv[4], wv[4];
      for (int i = 0; i < 4; ++i) xv[i] = Xt[kk][tn + 16 * i];
      for (int j = 0; j < 4; ++j) wv[j] = Wt[kk][to + 16 * j];
      for (int i = 0; i < 4; ++i)
        for (int j = 0; j < 4; ++j) acc[i][j] = fmaf(xv[i], wv[j], acc[i][j]);
    }
    __syncthreads();
  }
  float vm[4];
  for (int j = 0; j < 4; ++j) {
    int o = o0 + to + 16 * j;
    float gs = g[o] * BN_SCALE, bo = bb[o];
    float m = -INFINITY;
    for (int i = 0; i < 4; ++i) {
      float h = acc[i][j] * gs + bo;
      h = h >= 0.f ? h : 0.2f * h;
      m = fmaxf(m, h);
    }
    vm[j] = m;
  }
  for (int j = 0; j < 4; ++j) Xt[tn][to + 16 * j] = vm[j];
  __syncthreads();
  for (int s = 8; s > 0; s >>= 1) {
    if (tn < s)
      for (int j = 0; j < 4; ++j)
        Xt[tn][to + 16 * j] = fmaxf(Xt[tn][to + 16 * j], Xt[tn + s][to + 16 * j]);
    __syncthreads();
  }
  if (tn == 0)
    for (int j = 0; j < 4; ++j) {
      int o = o0 + to + 16 * j;
      partial[((long)b * gridDim.x + blockIdx.x) * O + o] = Xt[0][to + 16 * j];
    }
}

// ---------------- colmax_finish: out[b][o] = max_t partial[b][t][o] ----------------
__global__ void colmax_finish_kernel(const float* __restrict__ partial, int NT, int O,
                                     float* __restrict__ outp) {
  int b = blockIdx.y;
  int o = blockIdx.x * 256 + threadIdx.x;
  if (o >= O) return;
  float m = -INFINITY;
  for (int t = 0; t < NT; ++t) m = fmaxf(m, partial[((long)b * NT + t) * O + o]);
  outp[(long)b * O + o] = m;
}

// ---------------- FPS: SINGLE WAVE per batch. dist[32] in VGPRs (fits the ~92-reg cap);
// coords in LDS float4, swizzled so lane l's contiguous points l*32+i sit at slot i*64+l
// (ds_read_b128 at minimum 8 words/bank). 'last' point = one same-address b128 broadcast.
__global__ void __launch_bounds__(64, 1) fps_kernel(const float* __restrict__ xyz, int N, int M,
                                                    int* __restrict__ fpsIdx, float* __restrict__ node1) {
  #pragma clang fp contract(off)
  __shared__ float4 sp4[2048];  // point n at slot ((n&31)<<6)|(n>>5)
  __shared__ int fidx[512];
  int b = blockIdx.x, lane = threadIdx.x;
  const float* xb = xyz + (long)b * 3 * N;
  for (int n = lane; n < N; n += 64) {
    float xv = xb[n], yv = xb[N + n], zv = xb[2 * N + n];
    sp4[((n & 31) << 6) | (n >> 5)] = make_float4(xv, yv, zv, 0.f);
  }
  __syncthreads();
  float dist[32];
  #pragma unroll
  for (int i = 0; i < 32; ++i) dist[i] = 1e10f;
  int base = lane * 32;
  int last = 0;
  for (int it = 0; it < M; ++it) {
    if (lane == 0) fidx[it] = last;
    float4 lp = sp4[((last & 31) << 6) | (last >> 5)];  // same-address broadcast
    float best = -INFINITY; int bi = N;
    #pragma unroll
    for (int i = 0; i < 32; ++i) {
      // n = lane*32+i  ->  slot (i<<6)|lane
      float4 p = sp4[(i << 6) | lane];
      float dx = p.x - lp.x, dy = p.y - lp.y, dz = p.z - lp.z;
      float dx2 = dx * dx, dy2 = dy * dy, dz2 = dz * dz;
      float d = (dx2 + dy2) + dz2;
      float dn = dist[i];
      if (d < dn) dn = d;
      dist[i] = dn;
      if (dn > best) { best = dn; bi = base + i; }  // ascending -> first max in lane kept
    }
    // value-only butterfly -> global max in all lanes
    float gmax = best;
    #pragma unroll
    for (int off = 32; off > 0; off >>= 1) {
      float ov = __shfl_xor(gmax, off);
      gmax = fmaxf(gmax, ov);
    }
    // smallest lane holding gmax = first-occurrence argmax (contiguous ownership)
    unsigned long long mm = __ballot(best == gmax);
    int srcLane = (int)(__ffsll((long long)mm) - 1);
    last = __shfl(bi, srcLane);
  }
  // flush fpsIdx + node1
  for (int e = lane; e < M; e += 64) fpsIdx[(long)b * M + e] = fidx[e];
  for (int e = lane; e < 3 * M; e += 64) {
    int c = e / M, i = e % M;
    int src = fidx[i];
    float4 p = sp4[((src & 31) << 6) | (src >> 5)];
    node1[(long)b * 3 * M + e] = (c == 0) ? p.x : (c == 1) ? p.y : p.z;
  }
}

// ---------------- gather: out[b,c,i] = X[b,c,idx[b,i]] ----------------
__global__ void gather_kernel(const float* __restrict__ X, int xStrideB, int C, int N,
                              const int* __restrict__ idx, int M,
                              float* __restrict__ outp, int oStrideB, int B) {
  long t = (long)blockIdx.x * blockDim.x + threadIdx.x;
  long total = (long)B * C * M;
  if (t >= total) return;
  int i = (int)(t % M);
  int c = (int)((t / M) % C);
  int b = (int)(t / ((long)C * M));
  int src = idx[(long)b * M + i];
  outp[(long)b * oStrideB + (long)c * M + i] = X[(long)b * xStrideB + (long)c * N + src];
}

// ---------------- gathermax: out[b,c,i] = max_k X[b,c,idx[b,i,k]] ----------------
__global__ void gathermax_kernel(const float* __restrict__ X, int xStrideB, int C, int N,
                                 const int* __restrict__ idx, int k, int M,
                                 float* __restrict__ outp, int oStrideB, int B) {
  long t = (long)blockIdx.x * blockDim.x + threadIdx.x;
  long total = (long)B * C * M;
  if (t >= total) return;
  int i = (int)(t % M);
  int c = (int)((t / M) % C);
  int b = (int)(t / ((long)C * M));
  const int* ip = idx + ((long)b * M + i) * k;
  const float* xb = X + (long)b * xStrideB + (long)c * N;
  float best = -INFINITY;
  for (int kk = 0; kk < k; ++kk) best = fmaxf(best, xb[ip[kk]]);
  outp[(long)b * oStrideB + (long)c * M + i] = best;
}

// ---------------- head: v=[vf;vs] -> 3-layer MLP -> logits ----------------
__global__ void head_kernel(const float* __restrict__ vf, const float* __restrict__ vs,
                            const float* __restrict__ Wl1, const float* __restrict__ g6, const float* __restrict__ b6,
                            const float* __restrict__ Wl2, const float* __restrict__ bl2,
                            const float* __restrict__ g7, const float* __restrict__ b7,
                            const float* __restrict__ Wl3, const float* __restrict__ bl3,
                            float* __restrict__ logits) {
  __shared__ float v[2048];
  __shared__ float h1[512];
  __shared__ float h2[256];
  int b = blockIdx.x, tid = threadIdx.x;
  for (int c = tid; c < 1024; c += 256) {
    v[c]        = vf[(long)b * 1024 + c];
    v[1024 + c] = vs[(long)b * 1024 + c];
  }
  __syncthreads();
  for (int o = tid; o < 512; o += 256) {
    const float* wr = Wl1 + (long)o * 2048;
    float s = 0.f;
    for (int c = 0; c < 2048; c += 4) {
      float4 w4 = *(const float4*)(wr + c);
      s = fmaf(w4.x, v[c], s); s = fmaf(w4.y, v[c + 1], s);
      s = fmaf(w4.z, v[c + 2], s); s = fmaf(w4.w, v[c + 3], s);
    }
    float h = s * (g6[o] * BN_SCALE) + b6[o];
    h1[o] = h >= 0.f ? h : 0.2f * h;
  }
  __syncthreads();
  for (int o = tid; o < 256; o += 256) {
    const float* wr = Wl2 + (long)o * 512;
    float s = 0.f;
    for (int c = 0; c < 512; c += 4) {
      float4 w4 = *(const float4*)(wr + c);
      s = fmaf(w4.x, h1[c], s); s = fmaf(w4.y, h1[c + 1], s);
      s = fmaf(w4.z, h1[c + 2], s); s = fmaf(w4.w, h1[c + 3], s);
    }
    s += bl2[o];
    float h = s * (g7[o] * BN_SCALE) + b7[o];
    h2[o] = h >= 0.f ? h : 0.2f * h;
  }
  __syncthreads();
  if (tid < 40) {
    const float* wr = Wl3 + (long)tid * 256;
    float s = 0.f;
    for (int c = 0; c < 256; ++c) s = fmaf(wr[c], h2[c], s);
    logits[(long)b * 40 + tid] = s + bl3[tid];
  }
}

extern "C" void kernel_launch(void* const* d_in, const int* in_sizes, int n_in,
                              void* d_out, int out_size, void* d_ws, size_t ws_size,
                              hipStream_t stream) {
  const float* x   = (const float*)d_in[0];
  const float* W1  = (const float*)d_in[1];
  const float* g1  = (const float*)d_in[2];
  const float* b1  = (const float*)d_in[3];
  const float* W2  = (const float*)d_in[4];
  const float* g2  = (const float*)d_in[5];
  const float* b2  = (const float*)d_in[6];
  const float* W2m = (const float*)d_in[7];
  const float* g2m = (const float*)d_in[8];
  const float* b2m = (const float*)d_in[9];
  const float* W3  = (const float*)d_in[10];
  const float* g3  = (const float*)d_in[11];
  const float* b3  = (const float*)d_in[12];
  const float* W4  = (const float*)d_in[13];
  const float* g4  = (const float*)d_in[14];
  const float* b4  = (const float*)d_in[15];
  const float* W5  = (const float*)d_in[16];
  const float* g5  = (const float*)d_in[17];
  const float* b5  = (const float*)d_in[18];
  const float* Wl1 = (const float*)d_in[19];
  const float* g6  = (const float*)d_in[20];
  const float* b6  = (const float*)d_in[21];
  const float* Wl2 = (const float*)d_in[22];
  const float* bl2 = (const float*)d_in[23];
  const float* g7  = (const float*)d_in[24];
  const float* b7  = (const float*)d_in[25];
  const float* Wl3 = (const float*)d_in[26];
  const float* bl3 = (const float*)d_in[27];
  float* outF = (float*)d_out;

  const int B = 8, N = 2048, K = 20, M = 512, K2 = 10;

  float* ws   = (float*)d_ws;
  float* xt1  = ws;                              // (B,128,N)
  float* xm   = xt1 + (size_t)B * 128 * N;       // (B,256,M)
  float* xc   = xm  + (size_t)B * 256 * M;       // (B,512,M)
  float* Pt   = xc  + (size_t)B * 512 * M;       // (B,N,64)/(B,M,256)
  float* St   = Pt  + (size_t)B * N * 64;
  float* part = St  + (size_t)B * N * 64;        // (B,32,1024)
  float* vf   = part + (size_t)B * 32 * 1024;
  float* vs   = vf  + (size_t)B * 1024;
  float* sqa  = vs  + (size_t)B * 1024;
  float* sqb  = sqa + (size_t)B * N;
  float* sqn  = sqb + (size_t)B * N;
  int*   idxK = (int*)(sqn + (size_t)B * M);
  int*   fpsI = idxK + (size_t)B * N * K;

  float* logits = outF;        // (B,40)
  float* node1  = outF + 320;  // (B,3,M)

  dim3 t256(256);

  // ---- stage 1
  sqnorm_kernel<<<dim3((N + 255) / 256, B), t256, 0, stream>>>(x, 3 * N, 3, N, sqa);
  knn4_kernel<<<dim3(N / 4, B), t256, 0, stream>>>(x, 3 * N, x, 3 * N, sqa, sqa, 3, N, N, K, idxK);
  gemmT_kernel<<<dim3(N / 64, 1, B), t256, 0, stream>>>(x, 3 * N, 3, N, W1,     6, 64, Pt);
  gemmT_kernel<<<dim3(N / 64, 1, B), t256, 0, stream>>>(x, 3 * N, 3, N, W1 + 3, 6, 64, St);
  ecfinish_kernel<<<dim3(N / 4, B), dim3(64, 4), 0, stream>>>(Pt, St, idxK, K, 64, N, g1, b1, xt1, (long)128 * N);

  // FPS
  fps_kernel<<<dim3(B), dim3(64), 0, stream>>>(x, N, M, fpsI, node1);

  // ---- stage 2
  sqnorm_kernel<<<dim3((N + 255) / 256, B), t256, 0, stream>>>(xt1, 128 * N, 64, N, sqb);
  knn4_kernel<<<dim3(N / 4, B), t256, 0, stream>>>(xt1, 128 * N, xt1, 128 * N, sqb, sqb, 64, N, N, K, idxK);
  gemmT_kernel<<<dim3(N / 64, 1, B), t256, 0, stream>>>(xt1, 128 * N, 64, N, W2,      128, 64, Pt);
  gemmT_kernel<<<dim3(N / 64, 1, B), t256, 0, stream>>>(xt1, 128 * N, 64, N, W2 + 64, 128, 64, St);
  ecfinish_kernel<<<dim3(N / 4, B), dim3(64, 4), 0, stream>>>(Pt, St, idxK, K, 64, N, g2, b2,
                                                              xt1 + (size_t)64 * N, (long)128 * N);

  // ---- vf
  gemm_colmax_kernel<<<dim3(N / 64, 1024 / 64, B), t256, 0, stream>>>(xt1, 128 * N, 128, N, W2m, 128, 1024,
                                                                      g2m, b2m, part);
  colmax_finish_kernel<<<dim3(1024 / 256, B), t256, 0, stream>>>(part, N / 64, 1024, vf);

  // ---- nf1 gather
  gather_kernel<<<dim3((B * 128 * M + 255) / 256), t256, 0, stream>>>(xt1, 128 * N, 128, N, fpsI, M, xm, 256 * M, B);

  // ---- aggregate
  sqnorm_kernel<<<dim3((M + 255) / 256, B), t256, 0, stream>>>(node1, 3 * M, 3, M, sqn);
  knn4_kernel<<<dim3(M / 4, B), t256, 0, stream>>>(node1, 3 * M, x, 3 * N, sqn, sqa, 3, M, N, K, idxK);
  gathermax_kernel<<<dim3((B * 128 * M + 255) / 256), t256, 0, stream>>>(xt1, 128 * N, 128, N, idxK, K, M,
                                                                         xm + (size_t)128 * M, 256 * M, B);

  // ---- stage 3
  sqnorm_kernel<<<dim3((M + 255) / 256, B), t256, 0, stream>>>(xm, 256 * M, 256, M, sqb);
  knn4_kernel<<<dim3(M / 4, B), t256, 0, stream>>>(xm, 256 * M, xm, 256 * M, sqb, sqb, 256, M, M, K2, idxK);
  gemmT_kernel<<<dim3(M / 64, 256 / 64, B), t256, 0, stream>>>(xm, 256 * M, 256, M, W3,       512, 256, Pt);
  gemmT_kernel<<<dim3(M / 64, 256 / 64, B), t256, 0, stream>>>(xm, 256 * M, 256, M, W3 + 256, 512, 256, St);
  ecfinish_kernel<<<dim3(M, B), dim3(256, 1), 0, stream>>>(Pt, St, idxK, K2, 256, M, g3, b3, xc, (long)512 * M);

  // ---- stage 4
  sqnorm_kernel<<<dim3((M + 255) / 256, B), t256, 0, stream>>>(xc, 512 * M, 256, M, sqb);
  knn4_kernel<<<dim3(M / 4, B), t256, 0, stream>>>(xc, 512 * M, xc, 512 * M, sqb, sqb, 256, M, M, K2, idxK);
  gemmT_kernel<<<dim3(M / 64, 256 / 64, B), t256, 0, stream>>>(xc, 512 * M, 256, M, W4,       512, 256, Pt);
  gemmT_kernel<<<dim3(M / 64, 256 / 64, B), t256, 0, stream>>>(xc, 512 * M, 256, M, W4 + 256, 512, 256, St);
  ecfinish_kernel<<<dim3(M, B), dim3(256, 1), 0, stream>>>(Pt, St, idxK, K2, 256, M, g4, b4,
                                                           xc + (size_t)256 * M, (long)512 * M);

  // ---- vs
  gemm_colmax_kernel<<<dim3(M / 64, 1024 / 64, B), t256, 0, stream>>>(xc, 512 * M, 512, M, W5, 512, 1024,
                                                                      g5, b5, part);
  colmax_finish_kernel<<<dim3(1024 / 256, B), t256, 0, stream>>>(part, M / 64, 1024, vs);

  // ---- head
  head_kernel<<<dim3(B), t256, 0, stream>>>(vf, vs, Wl1, g6, b6, Wl2, bl2, g7, b7, Wl3, bl3, logits);
}

// Round 8
// 1899.511 us; speedup vs baseline: 1.1240x; 1.0962x over previous
//
#include <hip/hip_runtime.h>

#define BN_SCALE 0.9999950000374997f  // 1/sqrt(1+1e-5)

// ---------------- knn4: 4 queries/block; candidate sq-norm folded into dot loop.
// NOTE: the per-row constant -|q|^2 is dropped (top_k indices invariant to row shift).
__global__ void knn4_kernel(const float* __restrict__ Q, int qStrideB,
                            const float* __restrict__ Xc, int cStrideB,
                            int C, int M, int N, int k, int* __restrict__ idxOut) {
  __shared__ float qv[4][256];
  __shared__ float negd[4][2048];
  int b = blockIdx.y, q0 = blockIdx.x * 4, tid = threadIdx.x;
  for (int e = tid; e < 4 * C; e += 256) {
    int qq = e / C, c = e % C;
    qv[qq][c] = Q[(long)b * qStrideB + (long)c * M + (q0 + qq)];
  }
  __syncthreads();
  const float* cb = Xc + (long)b * cStrideB;
  for (int m = tid; m < N; m += 256) {
    float d0 = 0.f, d1 = 0.f, d2 = 0.f, d3 = 0.f, sq = 0.f;
    for (int c = 0; c < C; ++c) {
      float xv = cb[(long)c * N + m];
      d0 = fmaf(qv[0][c], xv, d0);
      d1 = fmaf(qv[1][c], xv, d1);
      d2 = fmaf(qv[2][c], xv, d2);
      d3 = fmaf(qv[3][c], xv, d3);
      sq = fmaf(xv, xv, sq);
    }
    negd[0][m] = 2.f * d0 - sq;
    negd[1][m] = 2.f * d1 - sq;
    negd[2][m] = 2.f * d2 - sq;
    negd[3][m] = 2.f * d3 - sq;
  }
  __syncthreads();
  int lane = tid & 63, w = tid >> 6;
  float* row = negd[w];
  int* outp = idxOut + ((long)b * M + (q0 + w)) * k;
  for (int kk = 0; kk < k; ++kk) {
    float best = -INFINITY; int bi = N;
    for (int m = lane; m < N; m += 64) {
      float v = row[m];
      if (v > best) { best = v; bi = m; }
    }
    for (int off = 32; off > 0; off >>= 1) {
      float ov = __shfl_xor(best, off);
      int   oi = __shfl_xor(bi, off);
      if (ov > best || (ov == best && oi < bi)) { best = ov; bi = oi; }
    }
    if (lane == (bi & 63)) row[bi] = -INFINITY;
    if (lane == 0) outp[kk] = bi;
  }
}

// ---------------- gemmPS: one pass computes BOTH halves of the edge-conv weight:
// PtT[b][n][o] = sum_c W[o*ldw+c]   * X[b][c][n]   (neighbor-weight block)
// StT[b][n][o] = sum_c W[o*ldw+C+c] * X[b][c][n]   (center-weight block)
__global__ void gemmPS_kernel(const float* __restrict__ X, int xStrideB, int C, int Np,
                              const float* __restrict__ W, int ldw, int O,
                              float* __restrict__ PtT, float* __restrict__ StT) {
  __shared__ float Wp[16][65];
  __shared__ float Ws[16][65];
  __shared__ float Xt[16][65];
  int b = blockIdx.z;
  int n0 = blockIdx.x * 64, o0 = blockIdx.y * 64;
  int tid = threadIdx.x;
  int to = tid % 16, tn = tid / 16;
  float accP[4][4] = {}, accS[4][4] = {};
  for (int c0 = 0; c0 < C; c0 += 16) {
    for (int e = tid; e < 16 * 64; e += 256) {
      int oo = e / 16, kk = e % 16;
      int c = c0 + kk, o = o0 + oo;
      bool ok = (c < C && o < O);
      Wp[kk][oo] = ok ? W[(long)o * ldw + c] : 0.f;
      Ws[kk][oo] = ok ? W[(long)o * ldw + C + c] : 0.f;
    }
    for (int e = tid; e < 16 * 64; e += 256) {
      int kk = e / 64, nn = e % 64;
      int c = c0 + kk, n = n0 + nn;
      Xt[kk][nn] = (c < C && n < Np) ? X[(long)b * xStrideB + (long)c * Np + n] : 0.f;
    }
    __syncthreads();
    for (int kk = 0; kk < 16; ++kk) {
      float xv[4], wp[4], ws[4];
      for (int i = 0; i < 4; ++i) xv[i] = Xt[kk][tn + 16 * i];
      for (int j = 0; j < 4; ++j) { wp[j] = Wp[kk][to + 16 * j]; ws[j] = Ws[kk][to + 16 * j]; }
      for (int i = 0; i < 4; ++i)
        for (int j = 0; j < 4; ++j) {
          accP[i][j] = fmaf(xv[i], wp[j], accP[i][j]);
          accS[i][j] = fmaf(xv[i], ws[j], accS[i][j]);
        }
    }
    __syncthreads();
  }
  for (int i = 0; i < 4; ++i) {
    int n = n0 + tn + 16 * i;
    if (n >= Np) continue;
    for (int j = 0; j < 4; ++j) {
      int o = o0 + to + 16 * j;
      if (o < O) {
        long off = ((long)b * Np + n) * O + o;
        PtT[off] = accP[i][j];
        StT[off] = accS[i][j];
      }
    }
  }
}

// ---------------- ecfinish: out[b,o,n] = lrelu(bn(S[n,o]-P[n,o] + max/min_k P[idx[n,k],o])) ----------------
__global__ void ecfinish_kernel(const float* __restrict__ Pt, const float* __restrict__ St,
                                const int* __restrict__ idx, int k, int O, int Np,
                                const float* __restrict__ g, const float* __restrict__ bb,
                                float* __restrict__ outp, long oStrideB) {
  int b = blockIdx.y;
  int n = blockIdx.x * blockDim.y + threadIdx.y;
  int o = threadIdx.x;
  const float* PtB = Pt + (long)b * Np * O;
  const float* StB = St + (long)b * Np * O;
  const int* ip = idx + ((long)b * Np + n) * k;
  float mx = -INFINITY, mn = INFINITY;
  for (int kk = 0; kk < k; ++kk) {
    float v = PtB[(long)ip[kk] * O + o];
    mx = fmaxf(mx, v); mn = fminf(mn, v);
  }
  float ctrP = PtB[(long)n * O + o];
  float ctrS = StB[(long)n * O + o];
  float gs = g[o] * BN_SCALE;
  float m = (gs >= 0.f) ? mx : mn;
  float h = (ctrS - ctrP + m) * gs + bb[o];
  outp[(long)b * oStrideB + (long)o * Np + n] = h >= 0.f ? h : 0.2f * h;
}

// ---------------- gemm_colmax: tile GEMM + lrelu(bn()) + max over n-tile -> partial[b][nt][o] ----------------
__global__ void gemm_colmax_kernel(const float* __restrict__ X, int xStrideB, int C, int Np,
                                   const float* __restrict__ W, int ldw, int O,
                                   const float* __restrict__ g, const float* __restrict__ bb,
                                   float* __restrict__ partial) {
  __shared__ float Wt[16][65];
  __shared__ float Xt[16][65];
  int b = blockIdx.z;
  int n0 = blockIdx.x * 64, o0 = blockIdx.y * 64;
  int tid = threadIdx.x;
  int to = tid % 16, tn = tid / 16;
  float acc[4][4] = {};
  for (int c0 = 0; c0 < C; c0 += 16) {
    for (int e = tid; e < 16 * 64; e += 256) {
      int oo = e / 16, kk = e % 16;
      int c = c0 + kk, o = o0 + oo;
      Wt[kk][oo] = (c < C && o < O) ? W[(long)o * ldw + c] : 0.f;
    }
    for (int e = tid; e < 16 * 64; e += 256) {
      int kk = e / 64, nn = e % 64;
      int c = c0 + kk, n = n0 + nn;
      Xt[kk][nn] = (c < C && n < Np) ? X[(long)b * xStrideB + (long)c * Np + n] : 0.f;
    }
    __syncthreads();
    for (int kk = 0; kk < 16; ++kk) {
      float xv[4], wv[4];
      for (int i = 0; i < 4; ++i) xv[i] = Xt[kk][tn + 16 * i];
      for (int j = 0; j < 4; ++j) wv[j] = Wt[kk][to + 16 * j];
      for (int i = 0; i < 4; ++i)
        for (int j = 0; j < 4; ++j) acc[i][j] = fmaf(xv[i], wv[j], acc[i][j]);
    }
    __syncthreads();
  }
  float vm[4];
  for (int j = 0; j < 4; ++j) {
    int o = o0 + to + 16 * j;
    float gs = g[o] * BN_SCALE, bo = bb[o];
    float m = -INFINITY;
    for (int i = 0; i < 4; ++i) {
      float h = acc[i][j] * gs + bo;
      h = h >= 0.f ? h : 0.2f * h;
      m = fmaxf(m, h);
    }
    vm[j] = m;
  }
  for (int j = 0; j < 4; ++j) Xt[tn][to + 16 * j] = vm[j];
  __syncthreads();
  for (int s = 8; s > 0; s >>= 1) {
    if (tn < s)
      for (int j = 0; j < 4; ++j)
        Xt[tn][to + 16 * j] = fmaxf(Xt[tn][to + 16 * j], Xt[tn + s][to + 16 * j]);
    __syncthreads();
  }
  if (tn == 0)
    for (int j = 0; j < 4; ++j) {
      int o = o0 + to + 16 * j;
      partial[((long)b * gridDim.x + blockIdx.x) * O + o] = Xt[0][to + 16 * j];
    }
}

// ---------------- FPS: single wave/batch (unchanged from R7) ----------------
__global__ void __launch_bounds__(64, 1) fps_kernel(const float* __restrict__ xyz, int N, int M,
                                                    int* __restrict__ fpsIdx, float* __restrict__ node1) {
  #pragma clang fp contract(off)
  __shared__ float4 sp4[2048];  // point n at slot ((n&31)<<6)|(n>>5)
  __shared__ int fidx[512];
  int b = blockIdx.x, lane = threadIdx.x;
  const float* xb = xyz + (long)b * 3 * N;
  for (int n = lane; n < N; n += 64) {
    float xv = xb[n], yv = xb[N + n], zv = xb[2 * N + n];
    sp4[((n & 31) << 6) | (n >> 5)] = make_float4(xv, yv, zv, 0.f);
  }
  __syncthreads();
  float dist[32];
  #pragma unroll
  for (int i = 0; i < 32; ++i) dist[i] = 1e10f;
  int base = lane * 32;
  int last = 0;
  for (int it = 0; it < M; ++it) {
    if (lane == 0) fidx[it] = last;
    float4 lp = sp4[((last & 31) << 6) | (last >> 5)];
    float best = -INFINITY; int bi = N;
    #pragma unroll
    for (int i = 0; i < 32; ++i) {
      float4 p = sp4[(i << 6) | lane];
      float dx = p.x - lp.x, dy = p.y - lp.y, dz = p.z - lp.z;
      float dx2 = dx * dx, dy2 = dy * dy, dz2 = dz * dz;
      float d = (dx2 + dy2) + dz2;
      float dn = dist[i];
      if (d < dn) dn = d;
      dist[i] = dn;
      if (dn > best) { best = dn; bi = base + i; }
    }
    float gmax = best;
    #pragma unroll
    for (int off = 32; off > 0; off >>= 1) {
      float ov = __shfl_xor(gmax, off);
      gmax = fmaxf(gmax, ov);
    }
    unsigned long long mm = __ballot(best == gmax);
    int srcLane = (int)(__ffsll((long long)mm) - 1);
    last = __shfl(bi, srcLane);
  }
  for (int e = lane; e < M; e += 64) fpsIdx[(long)b * M + e] = fidx[e];
  for (int e = lane; e < 3 * M; e += 64) {
    int c = e / M, i = e % M;
    int src = fidx[i];
    float4 p = sp4[((src & 31) << 6) | (src >> 5)];
    node1[(long)b * 3 * M + e] = (c == 0) ? p.x : (c == 1) ? p.y : p.z;
  }
}

// ---------------- xmfill: fused nf1 gather + aggregate gathermax ----------------
// xm[b][c][i]      = xt1[b][c][fpsI[b][i]]
// xm[b][128+c][i]  = max_k xt1[b][c][idxK[b][i][k]]
__global__ void xmfill_kernel(const float* __restrict__ xt1, int N,
                              const int* __restrict__ fpsI,
                              const int* __restrict__ idxK, int k, int M,
                              float* __restrict__ xm, int B) {
  long t = (long)blockIdx.x * blockDim.x + threadIdx.x;
  long total = (long)B * 128 * M;
  if (t >= total) return;
  int i = (int)(t % M);
  int c = (int)((t / M) % 128);
  int b = (int)(t / ((long)128 * M));
  const float* xb = xt1 + (long)b * 128 * N + (long)c * N;
  float* xmB = xm + (long)b * 256 * M;
  xmB[(long)c * M + i] = xb[fpsI[(long)b * M + i]];
  const int* ip = idxK + ((long)b * M + i) * k;
  float best = -INFINITY;
  for (int kk = 0; kk < k; ++kk) best = fmaxf(best, xb[ip[kk]]);
  xmB[(long)(128 + c) * M + i] = best;
}

// ---------------- head: fused colmax_finish + 3-layer MLP ----------------
__global__ void head_kernel(const float* __restrict__ partA, int NTa,
                            const float* __restrict__ partB, int NTb,
                            const float* __restrict__ Wl1, const float* __restrict__ g6, const float* __restrict__ b6,
                            const float* __restrict__ Wl2, const float* __restrict__ bl2,
                            const float* __restrict__ g7, const float* __restrict__ b7,
                            const float* __restrict__ Wl3, const float* __restrict__ bl3,
                            float* __restrict__ logits) {
  __shared__ float v[2048];
  __shared__ float h1[512];
  __shared__ float h2[256];
  int b = blockIdx.x, tid = threadIdx.x;
  for (int o = tid; o < 1024; o += 256) {
    float m = -INFINITY;
    for (int t = 0; t < NTa; ++t) m = fmaxf(m, partA[((long)b * NTa + t) * 1024 + o]);
    v[o] = m;
    float m2 = -INFINITY;
    for (int t = 0; t < NTb; ++t) m2 = fmaxf(m2, partB[((long)b * NTb + t) * 1024 + o]);
    v[1024 + o] = m2;
  }
  __syncthreads();
  for (int o = tid; o < 512; o += 256) {
    const float* wr = Wl1 + (long)o * 2048;
    float s = 0.f;
    for (int c = 0; c < 2048; c += 4) {
      float4 w4 = *(const float4*)(wr + c);
      s = fmaf(w4.x, v[c], s); s = fmaf(w4.y, v[c + 1], s);
      s = fmaf(w4.z, v[c + 2], s); s = fmaf(w4.w, v[c + 3], s);
    }
    float h = s * (g6[o] * BN_SCALE) + b6[o];
    h1[o] = h >= 0.f ? h : 0.2f * h;
  }
  __syncthreads();
  for (int o = tid; o < 256; o += 256) {
    const float* wr = Wl2 + (long)o * 512;
    float s = 0.f;
    for (int c = 0; c < 512; c += 4) {
      float4 w4 = *(const float4*)(wr + c);
      s = fmaf(w4.x, h1[c], s); s = fmaf(w4.y, h1[c + 1], s);
      s = fmaf(w4.z, h1[c + 2], s); s = fmaf(w4.w, h1[c + 3], s);
    }
    s += bl2[o];
    float h = s * (g7[o] * BN_SCALE) + b7[o];
    h2[o] = h >= 0.f ? h : 0.2f * h;
  }
  __syncthreads();
  if (tid < 40) {
    const float* wr = Wl3 + (long)tid * 256;
    float s = 0.f;
    for (int c = 0; c < 256; ++c) s = fmaf(wr[c], h2[c], s);
    logits[(long)b * 40 + tid] = s + bl3[tid];
  }
}

extern "C" void kernel_launch(void* const* d_in, const int* in_sizes, int n_in,
                              void* d_out, int out_size, void* d_ws, size_t ws_size,
                              hipStream_t stream) {
  const float* x   = (const float*)d_in[0];
  const float* W1  = (const float*)d_in[1];
  const float* g1  = (const float*)d_in[2];
  const float* b1  = (const float*)d_in[3];
  const float* W2  = (const float*)d_in[4];
  const float* g2  = (const float*)d_in[5];
  const float* b2  = (const float*)d_in[6];
  const float* W2m = (const float*)d_in[7];
  const float* g2m = (const float*)d_in[8];
  const float* b2m = (const float*)d_in[9];
  const float* W3  = (const float*)d_in[10];
  const float* g3  = (const float*)d_in[11];
  const float* b3  = (const float*)d_in[12];
  const float* W4  = (const float*)d_in[13];
  const float* g4  = (const float*)d_in[14];
  const float* b4  = (const float*)d_in[15];
  const float* W5  = (const float*)d_in[16];
  const float* g5  = (const float*)d_in[17];
  const float* b5  = (const float*)d_in[18];
  const float* Wl1 = (const float*)d_in[19];
  const float* g6  = (const float*)d_in[20];
  const float* b6  = (const float*)d_in[21];
  const float* Wl2 = (const float*)d_in[22];
  const float* bl2 = (const float*)d_in[23];
  const float* g7  = (const float*)d_in[24];
  const float* b7  = (const float*)d_in[25];
  const float* Wl3 = (const float*)d_in[26];
  const float* bl3 = (const float*)d_in[27];
  float* outF = (float*)d_out;

  const int B = 8, N = 2048, K = 20, M = 512, K2 = 10;

  float* ws    = (float*)d_ws;
  float* xt1   = ws;                               // (B,128,N)
  float* xm    = xt1 + (size_t)B * 128 * N;        // (B,256,M)
  float* xc    = xm  + (size_t)B * 256 * M;        // (B,512,M)
  float* Pt    = xc  + (size_t)B * 512 * M;        // max(B*N*64, B*M*256)
  float* St    = Pt  + (size_t)B * N * 64;
  float* partA = St  + (size_t)B * N * 64;         // (B,32,1024)
  float* partB = partA + (size_t)B * 32 * 1024;    // (B,8,1024)
  int*   idxK  = (int*)(partB + (size_t)B * 8 * 1024);  // (B,N,K)
  int*   fpsI  = idxK + (size_t)B * N * K;         // (B,M)

  float* logits = outF;        // (B,40)
  float* node1  = outF + 320;  // (B,3,M)

  dim3 t256(256);

  // ---- stage 1: knn(xyz) + edge_conv1 -> xt1 ch 0..63
  knn4_kernel<<<dim3(N / 4, B), t256, 0, stream>>>(x, 3 * N, x, 3 * N, 3, N, N, K, idxK);
  gemmPS_kernel<<<dim3(N / 64, 1, B), t256, 0, stream>>>(x, 3 * N, 3, N, W1, 6, 64, Pt, St);
  ecfinish_kernel<<<dim3(N / 4, B), dim3(64, 4), 0, stream>>>(Pt, St, idxK, K, 64, N, g1, b1, xt1, (long)128 * N);

  // FPS (xyz only)
  fps_kernel<<<dim3(B), dim3(64), 0, stream>>>(x, N, M, fpsI, node1);

  // ---- stage 2: knn(x1) + edge_conv2 -> xt1 ch 64..127
  knn4_kernel<<<dim3(N / 4, B), t256, 0, stream>>>(xt1, 128 * N, xt1, 128 * N, 64, N, N, K, idxK);
  gemmPS_kernel<<<dim3(N / 64, 1, B), t256, 0, stream>>>(xt1, 128 * N, 64, N, W2, 128, 64, Pt, St);
  ecfinish_kernel<<<dim3(N / 4, B), dim3(64, 4), 0, stream>>>(Pt, St, idxK, K, 64, N, g2, b2,
                                                              xt1 + (size_t)64 * N, (long)128 * N);

  // ---- vf partials
  gemm_colmax_kernel<<<dim3(N / 64, 1024 / 64, B), t256, 0, stream>>>(xt1, 128 * N, 128, N, W2m, 128, 1024,
                                                                      g2m, b2m, partA);

  // ---- aggregate knn (node1 vs xyz), then fused xm fill (nf1 gather + agg gathermax)
  knn4_kernel<<<dim3(M / 4, B), t256, 0, stream>>>(node1, 3 * M, x, 3 * N, 3, M, N, K, idxK);
  xmfill_kernel<<<dim3((B * 128 * M + 255) / 256), t256, 0, stream>>>(xt1, N, fpsI, idxK, K, M, xm, B);

  // ---- stage 3: knn(xm) + edge_conv3 -> xc ch 0..255
  knn4_kernel<<<dim3(M / 4, B), t256, 0, stream>>>(xm, 256 * M, xm, 256 * M, 256, M, M, K2, idxK);
  gemmPS_kernel<<<dim3(M / 64, 256 / 64, B), t256, 0, stream>>>(xm, 256 * M, 256, M, W3, 512, 256, Pt, St);
  ecfinish_kernel<<<dim3(M, B), dim3(256, 1), 0, stream>>>(Pt, St, idxK, K2, 256, M, g3, b3, xc, (long)512 * M);

  // ---- stage 4: knn(x3) + edge_conv4 -> xc ch 256..511
  knn4_kernel<<<dim3(M / 4, B), t256, 0, stream>>>(xc, 512 * M, xc, 512 * M, 256, M, M, K2, idxK);
  gemmPS_kernel<<<dim3(M / 64, 256 / 64, B), t256, 0, stream>>>(xc, 512 * M, 256, M, W4, 512, 256, Pt, St);
  ecfinish_kernel<<<dim3(M, B), dim3(256, 1), 0, stream>>>(Pt, St, idxK, K2, 256, M, g4, b4,
                                                           xc + (size_t)256 * M, (long)512 * M);

  // ---- vs partials
  gemm_colmax_kernel<<<dim3(M / 64, 1024 / 64, B), t256, 0, stream>>>(xc, 512 * M, 512, M, W5, 512, 1024,
                                                                      g5, b5, partB);

  // ---- head (fused colmax_finish + MLP)
  head_kernel<<<dim3(B), t256, 0, stream>>>(partA, N / 64, partB, M / 64,
                                            Wl1, g6, b6, Wl2, bl2, g7, b7, Wl3, bl3, logits);
}

// Round 9
// 1851.840 us; speedup vs baseline: 1.1529x; 1.0257x over previous
//
#include <hip/hip_runtime.h>

#define BN_SCALE 0.9999950000374997f  // 1/sqrt(1+1e-5)

// ---------------- knn4: 4 queries/block; candidate sq-norm folded into dot loop.
// NOTE: the per-row constant -|q|^2 is dropped (top_k indices invariant to row shift).
__global__ void knn4_kernel(const float* __restrict__ Q, int qStrideB,
                            const float* __restrict__ Xc, int cStrideB,
                            int C, int M, int N, int k, int* __restrict__ idxOut) {
  __shared__ float qv[4][256];
  __shared__ float negd[4][2048];
  int b = blockIdx.y, q0 = blockIdx.x * 4, tid = threadIdx.x;
  for (int e = tid; e < 4 * C; e += 256) {
    int qq = e / C, c = e % C;
    qv[qq][c] = Q[(long)b * qStrideB + (long)c * M + (q0 + qq)];
  }
  __syncthreads();
  const float* cb = Xc + (long)b * cStrideB;
  for (int m = tid; m < N; m += 256) {
    float d0 = 0.f, d1 = 0.f, d2 = 0.f, d3 = 0.f, sq = 0.f;
    for (int c = 0; c < C; ++c) {
      float xv = cb[(long)c * N + m];
      d0 = fmaf(qv[0][c], xv, d0);
      d1 = fmaf(qv[1][c], xv, d1);
      d2 = fmaf(qv[2][c], xv, d2);
      d3 = fmaf(qv[3][c], xv, d3);
      sq = fmaf(xv, xv, sq);
    }
    negd[0][m] = 2.f * d0 - sq;
    negd[1][m] = 2.f * d1 - sq;
    negd[2][m] = 2.f * d2 - sq;
    negd[3][m] = 2.f * d3 - sq;
  }
  __syncthreads();
  int lane = tid & 63, w = tid >> 6;
  float* row = negd[w];
  int* outp = idxOut + ((long)b * M + (q0 + w)) * k;
  for (int kk = 0; kk < k; ++kk) {
    float best = -INFINITY; int bi = N;
    for (int m = lane; m < N; m += 64) {
      float v = row[m];
      if (v > best) { best = v; bi = m; }
    }
    for (int off = 32; off > 0; off >>= 1) {
      float ov = __shfl_xor(best, off);
      int   oi = __shfl_xor(bi, off);
      if (ov > best || (ov == best && oi < bi)) { best = ov; bi = oi; }
    }
    if (lane == (bi & 63)) row[bi] = -INFINITY;
    if (lane == 0) outp[kk] = bi;
  }
}

// ---------------- gemmPS: one pass computes BOTH halves of the edge-conv weight ----------------
__global__ void gemmPS_kernel(const float* __restrict__ X, int xStrideB, int C, int Np,
                              const float* __restrict__ W, int ldw, int O,
                              float* __restrict__ PtT, float* __restrict__ StT) {
  __shared__ float Wp[16][65];
  __shared__ float Ws[16][65];
  __shared__ float Xt[16][65];
  int b = blockIdx.z;
  int n0 = blockIdx.x * 64, o0 = blockIdx.y * 64;
  int tid = threadIdx.x;
  int to = tid % 16, tn = tid / 16;
  float accP[4][4] = {}, accS[4][4] = {};
  for (int c0 = 0; c0 < C; c0 += 16) {
    for (int e = tid; e < 16 * 64; e += 256) {
      int oo = e / 16, kk = e % 16;
      int c = c0 + kk, o = o0 + oo;
      bool ok = (c < C && o < O);
      Wp[kk][oo] = ok ? W[(long)o * ldw + c] : 0.f;
      Ws[kk][oo] = ok ? W[(long)o * ldw + C + c] : 0.f;
    }
    for (int e = tid; e < 16 * 64; e += 256) {
      int kk = e / 64, nn = e % 64;
      int c = c0 + kk, n = n0 + nn;
      Xt[kk][nn] = (c < C && n < Np) ? X[(long)b * xStrideB + (long)c * Np + n] : 0.f;
    }
    __syncthreads();
    for (int kk = 0; kk < 16; ++kk) {
      float xv[4], wp[4], ws[4];
      for (int i = 0; i < 4; ++i) xv[i] = Xt[kk][tn + 16 * i];
      for (int j = 0; j < 4; ++j) { wp[j] = Wp[kk][to + 16 * j]; ws[j] = Ws[kk][to + 16 * j]; }
      for (int i = 0; i < 4; ++i)
        for (int j = 0; j < 4; ++j) {
          accP[i][j] = fmaf(xv[i], wp[j], accP[i][j]);
          accS[i][j] = fmaf(xv[i], ws[j], accS[i][j]);
        }
    }
    __syncthreads();
  }
  for (int i = 0; i < 4; ++i) {
    int n = n0 + tn + 16 * i;
    if (n >= Np) continue;
    for (int j = 0; j < 4; ++j) {
      int o = o0 + to + 16 * j;
      if (o < O) {
        long off = ((long)b * Np + n) * O + o;
        PtT[off] = accP[i][j];
        StT[off] = accS[i][j];
      }
    }
  }
}

// ---------------- ecfinish ----------------
__global__ void ecfinish_kernel(const float* __restrict__ Pt, const float* __restrict__ St,
                                const int* __restrict__ idx, int k, int O, int Np,
                                const float* __restrict__ g, const float* __restrict__ bb,
                                float* __restrict__ outp, long oStrideB) {
  int b = blockIdx.y;
  int n = blockIdx.x * blockDim.y + threadIdx.y;
  int o = threadIdx.x;
  const float* PtB = Pt + (long)b * Np * O;
  const float* StB = St + (long)b * Np * O;
  const int* ip = idx + ((long)b * Np + n) * k;
  float mx = -INFINITY, mn = INFINITY;
  for (int kk = 0; kk < k; ++kk) {
    float v = PtB[(long)ip[kk] * O + o];
    mx = fmaxf(mx, v); mn = fminf(mn, v);
  }
  float ctrP = PtB[(long)n * O + o];
  float ctrS = StB[(long)n * O + o];
  float gs = g[o] * BN_SCALE;
  float m = (gs >= 0.f) ? mx : mn;
  float h = (ctrS - ctrP + m) * gs + bb[o];
  outp[(long)b * oStrideB + (long)o * Np + n] = h >= 0.f ? h : 0.2f * h;
}

// ---------------- gemm_colmax ----------------
__global__ void gemm_colmax_kernel(const float* __restrict__ X, int xStrideB, int C, int Np,
                                   const float* __restrict__ W, int ldw, int O,
                                   const float* __restrict__ g, const float* __restrict__ bb,
                                   float* __restrict__ partial) {
  __shared__ float Wt[16][65];
  __shared__ float Xt[16][65];
  int b = blockIdx.z;
  int n0 = blockIdx.x * 64, o0 = blockIdx.y * 64;
  int tid = threadIdx.x;
  int to = tid % 16, tn = tid / 16;
  float acc[4][4] = {};
  for (int c0 = 0; c0 < C; c0 += 16) {
    for (int e = tid; e < 16 * 64; e += 256) {
      int oo = e / 16, kk = e % 16;
      int c = c0 + kk, o = o0 + oo;
      Wt[kk][oo] = (c < C && o < O) ? W[(long)o * ldw + c] : 0.f;
    }
    for (int e = tid; e < 16 * 64; e += 256) {
      int kk = e / 64, nn = e % 64;
      int c = c0 + kk, n = n0 + nn;
      Xt[kk][nn] = (c < C && n < Np) ? X[(long)b * xStrideB + (long)c * Np + n] : 0.f;
    }
    __syncthreads();
    for (int kk = 0; kk < 16; ++kk) {
      float xv[4], wv[4];
      for (int i = 0; i < 4; ++i) xv[i] = Xt[kk][tn + 16 * i];
      for (int j = 0; j < 4; ++j) wv[j] = Wt[kk][to + 16 * j];
      for (int i = 0; i < 4; ++i)
        for (int j = 0; j < 4; ++j) acc[i][j] = fmaf(xv[i], wv[j], acc[i][j]);
    }
    __syncthreads();
  }
  float vm[4];
  for (int j = 0; j < 4; ++j) {
    int o = o0 + to + 16 * j;
    float gs = g[o] * BN_SCALE, bo = bb[o];
    float m = -INFINITY;
    for (int i = 0; i < 4; ++i) {
      float h = acc[i][j] * gs + bo;
      h = h >= 0.f ? h : 0.2f * h;
      m = fmaxf(m, h);
    }
    vm[j] = m;
  }
  for (int j = 0; j < 4; ++j) Xt[tn][to + 16 * j] = vm[j];
  __syncthreads();
  for (int s = 8; s > 0; s >>= 1) {
    if (tn < s)
      for (int j = 0; j < 4; ++j)
        Xt[tn][to + 16 * j] = fmaxf(Xt[tn][to + 16 * j], Xt[tn + s][to + 16 * j]);
    __syncthreads();
  }
  if (tn == 0)
    for (int j = 0; j < 4; ++j) {
      int o = o0 + to + 16 * j;
      partial[((long)b * gridDim.x + blockIdx.x) * O + o] = Xt[0][to + 16 * j];
    }
}

// ---------------- FPS: 4 waves/batch, dist[8] in VGPRs, swizzled LDS float4 coords,
// per-wave ballot argmax, cross-wave parity double-buffer with ONE barrier/iter.
// Float math + tie-break order identical to prior rounds -> node1 bit-identical.
__global__ void __launch_bounds__(256, 1) fps_kernel(const float* __restrict__ xyz, int N, int M,
                                                     int* __restrict__ fpsIdx, float* __restrict__ node1) {
  #pragma clang fp contract(off)
  __shared__ float4 sp4[2048];   // point n at slot (n&7)*256 + (n>>3)
  __shared__ int fidx[512];
  __shared__ float wvs[2][4];
  __shared__ int   wis[2][4];
  int b = blockIdx.x, tid = threadIdx.x;
  int lane = tid & 63, w = tid >> 6;
  const float* xb = xyz + (long)b * 3 * N;
  for (int n = tid; n < N; n += 256) {
    sp4[((n & 7) << 8) | (n >> 3)] = make_float4(xb[n], xb[N + n], xb[2 * N + n], 0.f);
  }
  __syncthreads();
  float dist[8];
  #pragma unroll
  for (int i = 0; i < 8; ++i) dist[i] = 1e10f;
  int base = tid * 8;
  int last = 0;
  for (int it = 0; it < M; ++it) {
    int p = it & 1;
    if (tid == 0) fidx[it] = last;
    float4 lp = sp4[((last & 7) << 8) | (last >> 3)];  // same-address broadcast
    float best = -INFINITY; int bi = N;
    #pragma unroll
    for (int i = 0; i < 8; ++i) {
      float4 pt = sp4[(i << 8) | tid];   // point tid*8+i
      float dx = pt.x - lp.x, dy = pt.y - lp.y, dz = pt.z - lp.z;
      float dx2 = dx * dx, dy2 = dy * dy, dz2 = dz * dz;
      float d = (dx2 + dy2) + dz2;
      float dn = dist[i];
      if (d < dn) dn = d;
      dist[i] = dn;
      if (dn > best) { best = dn; bi = base + i; }  // ascending -> first max in lane kept
    }
    // per-wave: value butterfly then smallest lane holding the max
    float gmax = best;
    #pragma unroll
    for (int off = 32; off > 0; off >>= 1) {
      float ov = __shfl_xor(gmax, off);
      gmax = fmaxf(gmax, ov);
    }
    unsigned long long mm = __ballot(best == gmax);
    int srcLane = (int)(__ffsll((long long)mm) - 1);
    int wbi = __shfl(bi, srcLane);   // wave's first-occurrence argmax
    if (lane == 0) { wvs[p][w] = gmax; wis[p][w] = wbi; }
    __syncthreads();
    // all threads redundantly combine the 4 wave results (waves ascend in index)
    float bv = wvs[p][0]; int bbi = wis[p][0];
    #pragma unroll
    for (int ww = 1; ww < 4; ++ww) {
      float ov = wvs[p][ww]; int oi = wis[p][ww];
      if (ov > bv || (ov == bv && oi < bbi)) { bv = ov; bbi = oi; }
    }
    last = bbi;
    // parity: slot p rewritten only in iter it+2, after barrier it+1 -> safe with 1 barrier
  }
  for (int e = tid; e < M; e += 256) fpsIdx[(long)b * M + e] = fidx[e];
  for (int e = tid; e < 3 * M; e += 256) {
    int c = e / M, i = e % M;
    int src = fidx[i];
    float4 pt = sp4[((src & 7) << 8) | (src >> 3)];
    node1[(long)b * 3 * M + e] = (c == 0) ? pt.x : (c == 1) ? pt.y : pt.z;
  }
}

// ---------------- xmfill: fused nf1 gather + aggregate gathermax ----------------
__global__ void xmfill_kernel(const float* __restrict__ xt1, int N,
                              const int* __restrict__ fpsI,
                              const int* __restrict__ idxK, int k, int M,
                              float* __restrict__ xm, int B) {
  long t = (long)blockIdx.x * blockDim.x + threadIdx.x;
  long total = (long)B * 128 * M;
  if (t >= total) return;
  int i = (int)(t % M);
  int c = (int)((t / M) % 128);
  int b = (int)(t / ((long)128 * M));
  const float* xb = xt1 + (long)b * 128 * N + (long)c * N;
  float* xmB = xm + (long)b * 256 * M;
  xmB[(long)c * M + i] = xb[fpsI[(long)b * M + i]];
  const int* ip = idxK + ((long)b * M + i) * k;
  float best = -INFINITY;
  for (int kk = 0; kk < k; ++kk) best = fmaxf(best, xb[ip[kk]]);
  xmB[(long)(128 + c) * M + i] = best;
}

// ---------------- head: fused colmax_finish + 3-layer MLP ----------------
__global__ void head_kernel(const float* __restrict__ partA, int NTa,
                            const float* __restrict__ partB, int NTb,
                            const float* __restrict__ Wl1, const float* __restrict__ g6, const float* __restrict__ b6,
                            const float* __restrict__ Wl2, const float* __restrict__ bl2,
                            const float* __restrict__ g7, const float* __restrict__ b7,
                            const float* __restrict__ Wl3, const float* __restrict__ bl3,
                            float* __restrict__ logits) {
  __shared__ float v[2048];
  __shared__ float h1[512];
  __shared__ float h2[256];
  int b = blockIdx.x, tid = threadIdx.x;
  for (int o = tid; o < 1024; o += 256) {
    float m = -INFINITY;
    for (int t = 0; t < NTa; ++t) m = fmaxf(m, partA[((long)b * NTa + t) * 1024 + o]);
    v[o] = m;
    float m2 = -INFINITY;
    for (int t = 0; t < NTb; ++t) m2 = fmaxf(m2, partB[((long)b * NTb + t) * 1024 + o]);
    v[1024 + o] = m2;
  }
  __syncthreads();
  for (int o = tid; o < 512; o += 256) {
    const float* wr = Wl1 + (long)o * 2048;
    float s = 0.f;
    for (int c = 0; c < 2048; c += 4) {
      float4 w4 = *(const float4*)(wr + c);
      s = fmaf(w4.x, v[c], s); s = fmaf(w4.y, v[c + 1], s);
      s = fmaf(w4.z, v[c + 2], s); s = fmaf(w4.w, v[c + 3], s);
    }
    float h = s * (g6[o] * BN_SCALE) + b6[o];
    h1[o] = h >= 0.f ? h : 0.2f * h;
  }
  __syncthreads();
  for (int o = tid; o < 256; o += 256) {
    const float* wr = Wl2 + (long)o * 512;
    float s = 0.f;
    for (int c = 0; c < 512; c += 4) {
      float4 w4 = *(const float4*)(wr + c);
      s = fmaf(w4.x, h1[c], s); s = fmaf(w4.y, h1[c + 1], s);
      s = fmaf(w4.z, h1[c + 2], s); s = fmaf(w4.w, h1[c + 3], s);
    }
    s += bl2[o];
    float h = s * (g7[o] * BN_SCALE) + b7[o];
    h2[o] = h >= 0.f ? h : 0.2f * h;
  }
  __syncthreads();
  if (tid < 40) {
    const float* wr = Wl3 + (long)tid * 256;
    float s = 0.f;
    for (int c = 0; c < 256; ++c) s = fmaf(wr[c], h2[c], s);
    logits[(long)b * 40 + tid] = s + bl3[tid];
  }
}

extern "C" void kernel_launch(void* const* d_in, const int* in_sizes, int n_in,
                              void* d_out, int out_size, void* d_ws, size_t ws_size,
                              hipStream_t stream) {
  const float* x   = (const float*)d_in[0];
  const float* W1  = (const float*)d_in[1];
  const float* g1  = (const float*)d_in[2];
  const float* b1  = (const float*)d_in[3];
  const float* W2  = (const float*)d_in[4];
  const float* g2  = (const float*)d_in[5];
  const float* b2  = (const float*)d_in[6];
  const float* W2m = (const float*)d_in[7];
  const float* g2m = (const float*)d_in[8];
  const float* b2m = (const float*)d_in[9];
  const float* W3  = (const float*)d_in[10];
  const float* g3  = (const float*)d_in[11];
  const float* b3  = (const float*)d_in[12];
  const float* W4  = (const float*)d_in[13];
  const float* g4  = (const float*)d_in[14];
  const float* b4  = (const float*)d_in[15];
  const float* W5  = (const float*)d_in[16];
  const float* g5  = (const float*)d_in[17];
  const float* b5  = (const float*)d_in[18];
  const float* Wl1 = (const float*)d_in[19];
  const float* g6  = (const float*)d_in[20];
  const float* b6  = (const float*)d_in[21];
  const float* Wl2 = (const float*)d_in[22];
  const float* bl2 = (const float*)d_in[23];
  const float* g7  = (const float*)d_in[24];
  const float* b7  = (const float*)d_in[25];
  const float* Wl3 = (const float*)d_in[26];
  const float* bl3 = (const float*)d_in[27];
  float* outF = (float*)d_out;

  const int B = 8, N = 2048, K = 20, M = 512, K2 = 10;

  float* ws    = (float*)d_ws;
  float* xt1   = ws;                               // (B,128,N)
  float* xm    = xt1 + (size_t)B * 128 * N;        // (B,256,M)
  float* xc    = xm  + (size_t)B * 256 * M;        // (B,512,M)
  float* Pt    = xc  + (size_t)B * 512 * M;        // max(B*N*64, B*M*256)
  float* St    = Pt  + (size_t)B * N * 64;
  float* partA = St  + (size_t)B * N * 64;         // (B,32,1024)
  float* partB = partA + (size_t)B * 32 * 1024;    // (B,8,1024)
  int*   idxK  = (int*)(partB + (size_t)B * 8 * 1024);  // (B,N,K)
  int*   fpsI  = idxK + (size_t)B * N * K;         // (B,M)

  float* logits = outF;        // (B,40)
  float* node1  = outF + 320;  // (B,3,M)

  dim3 t256(256);

  // ---- stage 1: knn(xyz) + edge_conv1 -> xt1 ch 0..63
  knn4_kernel<<<dim3(N / 4, B), t256, 0, stream>>>(x, 3 * N, x, 3 * N, 3, N, N, K, idxK);
  gemmPS_kernel<<<dim3(N / 64, 1, B), t256, 0, stream>>>(x, 3 * N, 3, N, W1, 6, 64, Pt, St);
  ecfinish_kernel<<<dim3(N / 4, B), dim3(64, 4), 0, stream>>>(Pt, St, idxK, K, 64, N, g1, b1, xt1, (long)128 * N);

  // FPS (xyz only)
  fps_kernel<<<dim3(B), t256, 0, stream>>>(x, N, M, fpsI, node1);

  // ---- stage 2: knn(x1) + edge_conv2 -> xt1 ch 64..127
  knn4_kernel<<<dim3(N / 4, B), t256, 0, stream>>>(xt1, 128 * N, xt1, 128 * N, 64, N, N, K, idxK);
  gemmPS_kernel<<<dim3(N / 64, 1, B), t256, 0, stream>>>(xt1, 128 * N, 64, N, W2, 128, 64, Pt, St);
  ecfinish_kernel<<<dim3(N / 4, B), dim3(64, 4), 0, stream>>>(Pt, St, idxK, K, 64, N, g2, b2,
                                                              xt1 + (size_t)64 * N, (long)128 * N);

  // ---- vf partials
  gemm_colmax_kernel<<<dim3(N / 64, 1024 / 64, B), t256, 0, stream>>>(xt1, 128 * N, 128, N, W2m, 128, 1024,
                                                                      g2m, b2m, partA);

  // ---- aggregate knn (node1 vs xyz), then fused xm fill
  knn4_kernel<<<dim3(M / 4, B), t256, 0, stream>>>(node1, 3 * M, x, 3 * N, 3, M, N, K, idxK);
  xmfill_kernel<<<dim3((B * 128 * M + 255) / 256), t256, 0, stream>>>(xt1, N, fpsI, idxK, K, M, xm, B);

  // ---- stage 3: knn(xm) + edge_conv3 -> xc ch 0..255
  knn4_kernel<<<dim3(M / 4, B), t256, 0, stream>>>(xm, 256 * M, xm, 256 * M, 256, M, M, K2, idxK);
  gemmPS_kernel<<<dim3(M / 64, 256 / 64, B), t256, 0, stream>>>(xm, 256 * M, 256, M, W3, 512, 256, Pt, St);
  ecfinish_kernel<<<dim3(M, B), dim3(256, 1), 0, stream>>>(Pt, St, idxK, K2, 256, M, g3, b3, xc, (long)512 * M);

  // ---- stage 4: knn(x3) + edge_conv4 -> xc ch 256..511
  knn4_kernel<<<dim3(M / 4, B), t256, 0, stream>>>(xc, 512 * M, xc, 512 * M, 256, M, M, K2, idxK);
  gemmPS_kernel<<<dim3(M / 64, 256 / 64, B), t256, 0, stream>>>(xc, 512 * M, 256, M, W4, 512, 256, Pt, St);
  ecfinish_kernel<<<dim3(M, B), dim3(256, 1), 0, stream>>>(Pt, St, idxK, K2, 256, M, g4, b4,
                                                           xc + (size_t)256 * M, (long)512 * M);

  // ---- vs partials
  gemm_colmax_kernel<<<dim3(M / 64, 1024 / 64, B), t256, 0, stream>>>(xc, 512 * M, 512, M, W5, 512, 1024,
                                                                      g5, b5, partB);

  // ---- head (fused colmax_finish + MLP)
  head_kernel<<<dim3(B), t256, 0, stream>>>(partA, N / 64, partB, M / 64,
                                            Wl1, g6, b6, Wl2, bl2, g7, b7, Wl3, bl3, logits);
}